// Round 2
// baseline (102.000 us; speedup 1.0000x reference)
//
#include <hip/hip_runtime.h>

// Closs: B=8192 rows, N=2048 cols, half=1024.
// Per row: acc = sum_j (f[N-1-j] - f[j])                      (the "l" term)
//              + sum_{i=0}^{half-1} [ log S+_i + log S-_i ]
// where S±_i = sum_{j=i}^{half-1} ( exp(±f[j]) + exp(±f[N-1-j]) )
//   -> suffix sums of pairwise e±_j  -> prefix scan after index reversal.
// f ~ N(0,1) so direct exp-sums are safe in fp32 (no max subtraction needed).

#define NCOLS 2048
#define HALF  1024
#define TPB   256   // 4 pairs per thread

__global__ __launch_bounds__(TPB) void closs_row_kernel(const float* __restrict__ f,
                                                        float* __restrict__ partial) {
    const int row = blockIdx.x;
    const float* fr = f + (size_t)row * NCOLS;
    const int t    = threadIdx.x;
    const int lane = t & 63;
    const int wave = t >> 6;

    // Thread t owns k = 4t..4t+3 (k = distance from innermost window),
    // i.e. j = 1023-k in [1020-4t, 1024-4t).  Both loads are 16B-aligned float4
    // and fully coalesced across the block (descending order is still coalesced).
    const int jbase = HALF - 4 - 4 * t;                 // 1020 - 4t
    const float4 lo = *reinterpret_cast<const float4*>(fr + jbase);
    const float4 hi = *reinterpret_cast<const float4*>(fr + (NCOLS - 4 - jbase)); // mirrors
    const float* lop = reinterpret_cast<const float*>(&lo);
    const float* hip_ = reinterpret_cast<const float*>(&hi);

    // pair q (k = 4t+q): low = lo[3-q], mirror = hi[q]
    float pp[4], pm[4];          // intra-thread inclusive prefix of e+ / e-
    float sp = 0.f, sm = 0.f;    // thread totals
    float lsum = 0.f;            // contribution to l
    #pragma unroll
    for (int q = 0; q < 4; ++q) {
        const float a = lop[3 - q];
        const float b = hip_[q];
        const float ep = __expf(a) + __expf(b);
        const float em = __expf(-a) + __expf(-b);
        sp += ep; pp[q] = sp;
        sm += em; pm[q] = sm;
        lsum += b - a;
    }

    // Wave-level inclusive scan of thread totals (64 lanes).
    float ip = sp, im = sm;
    #pragma unroll
    for (int d = 1; d < 64; d <<= 1) {
        const float op = __shfl_up(ip, d, 64);
        const float om = __shfl_up(im, d, 64);
        if (lane >= d) { ip += op; im += om; }
    }

    // Cross-wave exclusive offsets (4 waves).
    __shared__ float wtp[4], wtm[4], cw[4];
    if (lane == 63) { wtp[wave] = ip; wtm[wave] = im; }
    __syncthreads();
    float offp = ip - sp;   // exclusive-within-wave
    float offm = im - sm;
    #pragma unroll
    for (int w = 0; w < 3; ++w) {
        if (w < wave) { offp += wtp[w]; offm += wtm[w]; }
    }

    // 8 logs per thread + l contribution.
    float c = lsum;
    #pragma unroll
    for (int q = 0; q < 4; ++q) {
        c += __logf(offp + pp[q]) + __logf(offm + pm[q]);
    }

    // Block reduction.
    #pragma unroll
    for (int d = 32; d > 0; d >>= 1) c += __shfl_down(c, d, 64);
    if (lane == 0) cw[wave] = c;
    __syncthreads();
    if (t == 0) partial[row] = cw[0] + cw[1] + cw[2] + cw[3];
}

__global__ __launch_bounds__(256) void closs_reduce_kernel(const float* __restrict__ partial,
                                                           float* __restrict__ out,
                                                           int n, double inv) {
    __shared__ double sd[256];
    double s = 0.0;
    for (int i = threadIdx.x; i < n; i += 256) s += (double)partial[i];
    sd[threadIdx.x] = s;
    __syncthreads();
    for (int step = 128; step > 0; step >>= 1) {
        if (threadIdx.x < step) sd[threadIdx.x] += sd[threadIdx.x + step];
        __syncthreads();
    }
    if (threadIdx.x == 0) out[0] = (float)(sd[0] * inv);
}

extern "C" void kernel_launch(void* const* d_in, const int* in_sizes, int n_in,
                              void* d_out, int out_size, void* d_ws, size_t ws_size,
                              hipStream_t stream) {
    const float* f = (const float*)d_in[0];
    const int Brows = in_sizes[0] / NCOLS;       // 8192
    float* partial = (float*)d_ws;               // Brows floats of scratch

    closs_row_kernel<<<Brows, TPB, 0, stream>>>(f, partial);
    closs_reduce_kernel<<<1, 256, 0, stream>>>(partial, (float*)d_out,
                                               Brows, 1.0 / (double)Brows);
}